// Round 4
// baseline (2081.794 us; speedup 1.0000x reference)
//
#include <hip/hip_runtime.h>

typedef __attribute__((ext_vector_type(8))) short short8;
typedef __attribute__((ext_vector_type(4))) float f32x4;

static constexpr int NB = 16;     // batch
static constexpr int NT = 128;    // seq len
static constexpr int NS = 1024;   // states
static constexpr int NV = 32000;  // vocab

// ---------- helpers ----------
__device__ __forceinline__ unsigned short f2bf(float f) {
  unsigned int u = __float_as_uint(f);
  u = (u + 0x7fffu + ((u >> 16) & 1u)) >> 16;   // RNE, inputs finite
  return (unsigned short)u;
}

__device__ __forceinline__ void lse_add(float& mx, float& s, float x) {
  float nm = fmaxf(mx, x);
  s = s * __expf(mx - nm) + __expf(x - nm);
  mx = nm;
}
__device__ __forceinline__ void lse_comb(float& mx, float& s, float m2, float s2) {
  float nm = fmaxf(mx, m2);
  s = s * __expf(mx - nm) + s2 * __expf(m2 - nm);
  mx = nm;
}

// agent-coherent (L3) accessors — bypass non-coherent L1/L2, NO cache-maintenance fences
__device__ __forceinline__ float4 ld_f4_agent(const float* p) {
  float4 r;
  asm volatile("global_load_dwordx4 %0, %1, off sc0 sc1" : "=v"(r) : "v"(p) : "memory");
  return r;
}
__device__ __forceinline__ float ld_f1_agent(const float* p) {
  float r;
  asm volatile("global_load_dword %0, %1, off sc0 sc1" : "=v"(r) : "v"(p) : "memory");
  return r;
}
__device__ __forceinline__ void st_f1_agent(float* p, float v) {
  __hip_atomic_store(p, v, __ATOMIC_RELAXED, __HIP_MEMORY_SCOPE_AGENT);
}

// ---------- phase A1: transition column LSE (log_softmax dim=0) + log_pi ----------
__global__ void __launch_bounds__(256)
prep_trans(const float* __restrict__ Tu, const float* __restrict__ prior,
           float* __restrict__ colLSE, float* __restrict__ log_pi) {
  __shared__ float smx[4][64];
  __shared__ float ssm[4][64];
  const int tid = threadIdx.x;
  const int wg = blockIdx.x;
  if (wg < 16) {
    const int col = wg * 64 + (tid & 63);
    const int seg = tid >> 6;
    float mx = -INFINITY, s = 0.f;
    const float* p = Tu + (size_t)(seg * 256) * NS + col;
    for (int m = 0; m < 256; ++m) lse_add(mx, s, p[(size_t)m * NS]);
    smx[seg][tid & 63] = mx;
    ssm[seg][tid & 63] = s;
    __syncthreads();
    if (tid < 64) {
      float M = smx[0][tid], S = ssm[0][tid];
      for (int k = 1; k < 4; ++k) lse_comb(M, S, smx[k][tid], ssm[k][tid]);
      colLSE[wg * 64 + tid] = M + __logf(S);
    }
  } else {
    float mx = -INFINITY, s = 0.f;
    for (int i = tid; i < NS; i += 256) lse_add(mx, s, prior[i]);
    for (int o = 1; o < 64; o <<= 1) {
      float m2 = __shfl_xor(mx, o), s2 = __shfl_xor(s, o);
      lse_comb(mx, s, m2, s2);
    }
    const int wv = tid >> 6, ln = tid & 63;
    if (ln == 0) { smx[0][wv] = mx; ssm[0][wv] = s; }
    __syncthreads();
    float M = smx[0][0], S = ssm[0][0];
    for (int k = 1; k < 4; ++k) lse_comb(M, S, smx[0][k], ssm[0][k]);
    const float lse = M + __logf(S);
    for (int i = tid; i < NS; i += 256) log_pi[i] = prior[i] - lse;
  }
}

// ---------- phase A2: T_prob[m][n] = exp(Tu[m][n] - colLSE[n]) as bf16 ----------
__global__ void __launch_bounds__(256)
prep_tprob(const float* __restrict__ Tu, const float* __restrict__ colLSE,
           unsigned short* __restrict__ Tp) {
  const int i = (blockIdx.x * 256 + threadIdx.x) * 4;
  const float4 tu = *(const float4*)(Tu + i);
  const float4 cl = *(const float4*)(colLSE + (i & (NS - 1)));
  ushort4 o;
  o.x = f2bf(__expf(tu.x - cl.x));
  o.y = f2bf(__expf(tu.y - cl.y));
  o.z = f2bf(__expf(tu.z - cl.z));
  o.w = f2bf(__expf(tu.w - cl.w));
  *(ushort4*)(Tp + i) = o;
}

// ---------- phase A3: emission row LSE (online) + token gather ----------
__global__ void __launch_bounds__(256)
prep_emit(const float* __restrict__ Em, const int* __restrict__ tok,
          float* __restrict__ emit_g) {
  __shared__ float wm[4], wsv[4];
  const int n = blockIdx.x;
  const int tid = threadIdx.x;
  const float* row = Em + (size_t)n * NV;
  float mx = -INFINITY, s = 0.f;
  for (int i = tid; i < NV; i += 256) lse_add(mx, s, row[i]);
  for (int o = 1; o < 64; o <<= 1) {
    float m2 = __shfl_xor(mx, o), s2 = __shfl_xor(s, o);
    lse_comb(mx, s, m2, s2);
  }
  const int wv = tid >> 6, ln = tid & 63;
  if (ln == 0) { wm[wv] = mx; wsv[wv] = s; }
  __syncthreads();
  float M = wm[0], S = wsv[0];
  for (int k = 1; k < 4; ++k) lse_comb(M, S, wm[k], wsv[k]);
  const float lse = M + __logf(S);
  for (int j = tid; j < NB * NT; j += 256)
    emit_g[(size_t)j * NS + n] = row[tok[j]] - lse;
}

// ---------- phase B: ONE barrier group of 4 wgs; batches are MFMA columns ----------
// wg w owns output states [w*256, w*256+256). T slice in VGPRs (128/lane).
// Per step: spin -> sc1-gather full alpha (all 16 batches) -> exp to LDS ->
// 32 MFMAs (B cols = batches) -> sc1-store own slice + per-b max -> bump ctr.
__global__ void __launch_bounds__(1024)
hmm_chain4(const unsigned short* __restrict__ Tp, const float* __restrict__ emit_g,
           const float* __restrict__ log_pi, const int* __restrict__ length,
           float* __restrict__ alpha, float* __restrict__ wgm,
           unsigned int* __restrict__ bar, float* __restrict__ out) {
  __shared__ __align__(16) unsigned short explds[16 * 1032];  // [b][k], pitch 1032 (pad: 2-way banks)
  __shared__ float wmx[16][17];
  __shared__ float psum[64][17];
  __shared__ float psum2[16][17];
  __shared__ int len_s[16];
  __shared__ unsigned int outmsk[NT];

  const int tid  = threadIdx.x;
  const int wgid = blockIdx.x;       // 0..3
  const int lane = tid & 63;
  const int wv   = tid >> 6;         // wave 0..15
  const int b2   = tid & 15;         // this thread's batch (gather/epilogue); == lane&15
  const int kc   = tid >> 4;         // k-chunk 0..63 (gather)
  const int kg   = lane >> 4;        // 0..3
  const int mbase = wgid * 256 + wv * 16;   // wave's 16 output rows
  const int m0 = mbase + kg * 4;            // epilogue rows m0..m0+3 (D: row=(lane>>4)*4+r)
  unsigned int* ctr = bar;

  // T fragments (A-operand, VALIDATED r3): row = mbase+(lane&15), k = kk*32+(lane>>4)*8+j
  short8 tf[32];
  {
    const unsigned short* tb = Tp + (size_t)(mbase + (lane & 15)) * NS + kg * 8;
#pragma unroll
    for (int i = 0; i < 32; ++i) tf[i] = *(const short8*)(tb + i * 32);
  }

  // lengths + per-t output bitmask
  if (tid < 16) {
    int l = length[tid];
    len_s[tid] = l < 1 ? 1 : (l > NT ? NT : l);
  }
  __syncthreads();
  if (tid < NT) {
    unsigned m = 0;
#pragma unroll
    for (int b = 0; b < 16; ++b) m |= (unsigned)(len_s[b] - 1 == tid) << b;
    outmsk[tid] = m;
  }

  // ---- produce alpha0 (parity 0): thread -> (b2, rows wgid*256 + (tid>>4)*4)
  {
    const int mm = wgid * 256 + (tid >> 4) * 4;
    const float4 e  = *(const float4*)(emit_g + ((size_t)b2 * NT) * NS + mm);
    const float4 lp = *(const float4*)(log_pi + mm);
    float4 r;
    r.x = e.x + lp.x; r.y = e.y + lp.y; r.z = e.z + lp.z; r.w = e.w + lp.w;
    float* op = alpha + b2 * NS + mm;
    st_f1_agent(op + 0, r.x); st_f1_agent(op + 1, r.y);
    st_f1_agent(op + 2, r.z); st_f1_agent(op + 3, r.w);
    float lm = fmaxf(fmaxf(r.x, r.y), fmaxf(r.z, r.w));
    lm = fmaxf(lm, __shfl_xor(lm, 16));
    lm = fmaxf(lm, __shfl_xor(lm, 32));
    if (lane < 16) wmx[wv][lane] = lm;
  }
  __syncthreads();
  if (tid < 16) {
    float m = wmx[0][tid];
#pragma unroll
    for (int w = 1; w < 16; ++w) m = fmaxf(m, wmx[w][tid]);
    st_f1_agent(wgm + 0 * 64 + wgid * 16 + tid, m);
  }
  asm volatile("s_waitcnt vmcnt(0)" ::: "memory");
  __syncthreads();
  if (tid == 0) __hip_atomic_fetch_add(ctr, 1u, __ATOMIC_RELAXED, __HIP_MEMORY_SCOPE_AGENT);

  // ---- main recurrence: step t consumes alpha_t, produces alpha_{t+1}
  for (int t = 0; t < NT - 1; ++t) {
    if (tid == 0) {
      while (__hip_atomic_load(ctr, __ATOMIC_RELAXED, __HIP_MEMORY_SCOPE_AGENT) < 4u * (t + 1)) {}
    }
    __syncthreads();
    const int par = t & 1;
    const float* bufT = alpha + par * (NB * NS);

    // emit prefetch for epilogue (independent of alpha -> hides under gather)
    const float4 em = *(const float4*)(emit_g + ((size_t)b2 * NT + (t + 1)) * NS + m0);

    // gather alpha_t: 16 floats (b2, k=kc*16..+16) + 4 per-wg maxes, all L3-coherent
    float4 q0, q1, q2, q3;
    {
      const float* gp = bufT + b2 * NS + kc * 16;
      asm volatile("global_load_dwordx4 %0, %1, off sc0 sc1" : "=v"(q0) : "v"(gp)      : "memory");
      asm volatile("global_load_dwordx4 %0, %1, off sc0 sc1" : "=v"(q1) : "v"(gp + 4)  : "memory");
      asm volatile("global_load_dwordx4 %0, %1, off sc0 sc1" : "=v"(q2) : "v"(gp + 8)  : "memory");
      asm volatile("global_load_dwordx4 %0, %1, off sc0 sc1" : "=v"(q3) : "v"(gp + 12) : "memory");
    }
    float w0, w1, w2, w3;
    {
      const float* wp = wgm + par * 64 + b2;
      asm volatile("global_load_dword %0, %1, off sc0 sc1" : "=v"(w0) : "v"(wp)      : "memory");
      asm volatile("global_load_dword %0, %1, off sc0 sc1" : "=v"(w1) : "v"(wp + 16) : "memory");
      asm volatile("global_load_dword %0, %1, off sc0 sc1" : "=v"(w2) : "v"(wp + 32) : "memory");
      asm volatile("global_load_dword %0, %1, off sc0 sc1" : "=v"(w3) : "v"(wp + 48) : "memory");
    }
    asm volatile("s_waitcnt vmcnt(0)" ::: "memory");
    __builtin_amdgcn_sched_barrier(0);
    const float amax = fmaxf(fmaxf(w0, w1), fmaxf(w2, w3));

    // exp + partial sum + pack bf16 -> LDS B operand explds[b][k]
    float g[16] = {q0.x, q0.y, q0.z, q0.w, q1.x, q1.y, q1.z, q1.w,
                   q2.x, q2.y, q2.z, q2.w, q3.x, q3.y, q3.z, q3.w};
    float s = 0.f;
    short8 v0, v1;
#pragma unroll
    for (int i = 0; i < 8; ++i) {
      float e = __expf(g[i] - amax);      s += e; v0[i] = (short)f2bf(e);
      float e2 = __expf(g[8 + i] - amax); s += e2; v1[i] = (short)f2bf(e2);
    }
    *(short8*)(explds + b2 * 1032 + kc * 16)     = v0;
    *(short8*)(explds + b2 * 1032 + kc * 16 + 8) = v1;

    const unsigned umsk = outmsk[t];
    if (umsk && wgid == 0) psum[kc][b2] = s;
    __syncthreads();                       // B operand (+psum) ready
    if (umsk && wgid == 0) {
      if (tid < 256) {
        const int bb = tid & 15, qq = tid >> 4;
        psum2[qq][bb] = (psum[qq * 4][bb] + psum[qq * 4 + 1][bb]) +
                        (psum[qq * 4 + 2][bb] + psum[qq * 4 + 3][bb]);
      }
      __syncthreads();
      if (tid < 16 && ((umsk >> tid) & 1)) {
        float ss = 0.f;
#pragma unroll
        for (int qq = 0; qq < 16; ++qq) ss += psum2[qq][tid];
        out[tid] = amax + __logf(ss);      // this thread's amax is for b=tid
      }
    }

    // MFMA: S[m][b] = sum_k T[m][k] * exp(alpha[b][k]-amax[b]); B col = batch
    f32x4 a0 = {0.f, 0.f, 0.f, 0.f}, a1 = a0, a2 = a0, a3 = a0;
    const unsigned short* Bb = explds + (lane & 15) * 1032 + kg * 8;
#pragma unroll
    for (int kk = 0; kk < 32; kk += 4) {
      a0 = __builtin_amdgcn_mfma_f32_16x16x32_bf16(tf[kk + 0], *(const short8*)(Bb + (kk + 0) * 32), a0, 0, 0, 0);
      a1 = __builtin_amdgcn_mfma_f32_16x16x32_bf16(tf[kk + 1], *(const short8*)(Bb + (kk + 1) * 32), a1, 0, 0, 0);
      a2 = __builtin_amdgcn_mfma_f32_16x16x32_bf16(tf[kk + 2], *(const short8*)(Bb + (kk + 2) * 32), a2, 0, 0, 0);
      a3 = __builtin_amdgcn_mfma_f32_16x16x32_bf16(tf[kk + 3], *(const short8*)(Bb + (kk + 3) * 32), a3, 0, 0, 0);
    }
    const f32x4 Sv = (a0 + a1) + (a2 + a3);

    // epilogue: alpha_{t+1}[b2][m0..m0+3] = emit + amax + ln(S)
    const int pn = par ^ 1;
    float* op = alpha + pn * (NB * NS) + b2 * NS + m0;
    float4 r;
    r.x = em.x + amax + 0.6931471805599453f * __log2f(Sv[0]);
    r.y = em.y + amax + 0.6931471805599453f * __log2f(Sv[1]);
    r.z = em.z + amax + 0.6931471805599453f * __log2f(Sv[2]);
    r.w = em.w + amax + 0.6931471805599453f * __log2f(Sv[3]);
    st_f1_agent(op + 0, r.x); st_f1_agent(op + 1, r.y);
    st_f1_agent(op + 2, r.z); st_f1_agent(op + 3, r.w);

    float lm = fmaxf(fmaxf(r.x, r.y), fmaxf(r.z, r.w));
    lm = fmaxf(lm, __shfl_xor(lm, 16));
    lm = fmaxf(lm, __shfl_xor(lm, 32));
    if (lane < 16) wmx[wv][lane] = lm;
    __syncthreads();
    if (tid < 16) {
      float m = wmx[0][tid];
#pragma unroll
      for (int w = 1; w < 16; ++w) m = fmaxf(m, wmx[w][tid]);
      st_f1_agent(wgm + pn * 64 + wgid * 16 + tid, m);
    }
    asm volatile("s_waitcnt vmcnt(0)" ::: "memory");
    __syncthreads();
    if (tid == 0) __hip_atomic_fetch_add(ctr, 1u, __ATOMIC_RELAXED, __HIP_MEMORY_SCOPE_AGENT);
  }

  // ---- outputs for len == NT (alpha_{127}, parity 1)
  const unsigned mlast = outmsk[NT - 1];
  if (mlast && wgid == 0) {
    if (tid == 0) {
      while (__hip_atomic_load(ctr, __ATOMIC_RELAXED, __HIP_MEMORY_SCOPE_AGENT) < 4u * NT) {}
    }
    __syncthreads();
    const float* bufT = alpha + ((NT - 1) & 1) * (NB * NS);
    float4 q0, q1, q2, q3;
    const float* gp = bufT + b2 * NS + kc * 16;
    asm volatile("global_load_dwordx4 %0, %1, off sc0 sc1" : "=v"(q0) : "v"(gp)      : "memory");
    asm volatile("global_load_dwordx4 %0, %1, off sc0 sc1" : "=v"(q1) : "v"(gp + 4)  : "memory");
    asm volatile("global_load_dwordx4 %0, %1, off sc0 sc1" : "=v"(q2) : "v"(gp + 8)  : "memory");
    asm volatile("global_load_dwordx4 %0, %1, off sc0 sc1" : "=v"(q3) : "v"(gp + 12) : "memory");
    float w0, w1, w2, w3;
    const float* wp = wgm + ((NT - 1) & 1) * 64 + b2;
    asm volatile("global_load_dword %0, %1, off sc0 sc1" : "=v"(w0) : "v"(wp)      : "memory");
    asm volatile("global_load_dword %0, %1, off sc0 sc1" : "=v"(w1) : "v"(wp + 16) : "memory");
    asm volatile("global_load_dword %0, %1, off sc0 sc1" : "=v"(w2) : "v"(wp + 32) : "memory");
    asm volatile("global_load_dword %0, %1, off sc0 sc1" : "=v"(w3) : "v"(wp + 48) : "memory");
    asm volatile("s_waitcnt vmcnt(0)" ::: "memory");
    __builtin_amdgcn_sched_barrier(0);
    const float amax = fmaxf(fmaxf(w0, w1), fmaxf(w2, w3));
    float g[16] = {q0.x, q0.y, q0.z, q0.w, q1.x, q1.y, q1.z, q1.w,
                   q2.x, q2.y, q2.z, q2.w, q3.x, q3.y, q3.z, q3.w};
    float s = 0.f;
#pragma unroll
    for (int i = 0; i < 16; ++i) s += __expf(g[i] - amax);
    psum[kc][b2] = s;
    __syncthreads();
    if (tid < 256) {
      const int bb = tid & 15, qq = tid >> 4;
      psum2[qq][bb] = (psum[qq * 4][bb] + psum[qq * 4 + 1][bb]) +
                      (psum[qq * 4 + 2][bb] + psum[qq * 4 + 3][bb]);
    }
    __syncthreads();
    if (tid < 16 && ((mlast >> tid) & 1)) {
      float ss = 0.f;
#pragma unroll
      for (int qq = 0; qq < 16; ++qq) ss += psum2[qq][tid];
      out[tid] = amax + __logf(ss);
    }
  }
}

// ---------- launch ----------
extern "C" void kernel_launch(void* const* d_in, const int* in_sizes, int n_in,
                              void* d_out, int out_size, void* d_ws, size_t ws_size,
                              hipStream_t stream) {
  const float* Em = (const float*)d_in[0];   // emission (N,V)
  const float* Tu = (const float*)d_in[1];   // transition (N,N)
  const float* Pr = (const float*)d_in[2];   // priors (N,)
  const int*   tok = (const int*)d_in[3];    // (B,T)
  const int*   len = (const int*)d_in[4];    // (B,)
  float* out = (float*)d_out;
  char* ws = (char*)d_ws;

  float* colLSE      = (float*)(ws + 0);            // 4 KB
  float* log_pi      = (float*)(ws + 4096);         // 4 KB
  unsigned int* bar  = (unsigned int*)(ws + 8192);  // ctr
  float* wgm         = (float*)(ws + 12288);        // [2][4][16] per-wg per-b maxes
  float* alpha       = (float*)(ws + 16384);        // [2][16][1024] f32 = 128 KB
  unsigned short* Tp = (unsigned short*)(ws + (256 << 10));  // 2 MB bf16
  float* emit_g      = (float*)(ws + (4u << 20));   // 8 MB

  hipMemsetAsync(bar, 0, 1024, stream);
  prep_trans<<<17, 256, 0, stream>>>(Tu, Pr, colLSE, log_pi);
  prep_tprob<<<(NS * NS) / (256 * 4), 256, 0, stream>>>(Tu, colLSE, Tp);
  prep_emit<<<NS, 256, 0, stream>>>(Em, tok, emit_g);

  void* args[] = {(void*)&Tp, (void*)&emit_g, (void*)&log_pi, (void*)&len,
                  (void*)&alpha, (void*)&wgm, (void*)&bar, (void*)&out};
  hipError_t e = hipLaunchCooperativeKernel((void*)hmm_chain4, dim3(4), dim3(1024),
                                            args, 0, stream);
  if (e != hipSuccess) {
    // 4 blocks on a 256-CU device are trivially co-resident
    hmm_chain4<<<dim3(4), dim3(1024), 0, stream>>>(Tp, emit_g, log_pi, len,
                                                   alpha, wgm, bar, out);
  }
}

// Round 5
// 723.129 us; speedup vs baseline: 2.8789x; 2.8789x over previous
//
#include <hip/hip_runtime.h>

typedef __attribute__((ext_vector_type(8))) short short8;
typedef __attribute__((ext_vector_type(4))) float f32x4;
typedef __attribute__((ext_vector_type(2))) unsigned int uint2_t;

static constexpr int NB = 16;     // batch
static constexpr int NT = 128;    // seq len
static constexpr int NS = 1024;   // states
static constexpr int NV = 32000;  // vocab
static constexpr int NJ = NB * NT;  // 2048

// ---------- helpers ----------
__device__ __forceinline__ unsigned short f2bf(float f) {
  unsigned int u = __float_as_uint(f);
  u = (u + 0x7fffu + ((u >> 16) & 1u)) >> 16;   // RNE, finite inputs
  return (unsigned short)u;
}
__device__ __forceinline__ float bf2f(unsigned short h) {
  return __uint_as_float(((unsigned int)h) << 16);
}
__device__ __forceinline__ void lse_add(float& mx, float& s, float x) {
  float nm = fmaxf(mx, x);
  s = s * __expf(mx - nm) + __expf(x - nm);
  mx = nm;
}
__device__ __forceinline__ void lse_comb(float& mx, float& s, float m2, float s2) {
  float nm = fmaxf(mx, m2);
  s = s * __expf(mx - nm) + s2 * __expf(m2 - nm);
  mx = nm;
}

// ---------- phase A1: transition column LSE (log_softmax dim=0) + log_pi ----------
__global__ void __launch_bounds__(256)
prep_trans(const float* __restrict__ Tu, const float* __restrict__ prior,
           float* __restrict__ colLSE, float* __restrict__ log_pi) {
  __shared__ float smx[4][64];
  __shared__ float ssm[4][64];
  const int tid = threadIdx.x;
  const int wg = blockIdx.x;
  if (wg < 16) {
    const int col = wg * 64 + (tid & 63);
    const int seg = tid >> 6;
    float mx = -INFINITY, s = 0.f;
    const float* p = Tu + (size_t)(seg * 256) * NS + col;
    for (int m = 0; m < 256; ++m) lse_add(mx, s, p[(size_t)m * NS]);
    smx[seg][tid & 63] = mx;
    ssm[seg][tid & 63] = s;
    __syncthreads();
    if (tid < 64) {
      float M = smx[0][tid], S = ssm[0][tid];
      for (int k = 1; k < 4; ++k) lse_comb(M, S, smx[k][tid], ssm[k][tid]);
      colLSE[wg * 64 + tid] = M + __logf(S);
    }
  } else {
    float mx = -INFINITY, s = 0.f;
    for (int i = tid; i < NS; i += 256) lse_add(mx, s, prior[i]);
    for (int o = 1; o < 64; o <<= 1) {
      float m2 = __shfl_xor(mx, o), s2 = __shfl_xor(s, o);
      lse_comb(mx, s, m2, s2);
    }
    const int wv = tid >> 6, ln = tid & 63;
    if (ln == 0) { smx[0][wv] = mx; ssm[0][wv] = s; }
    __syncthreads();
    float M = smx[0][0], S = ssm[0][0];
    for (int k = 1; k < 4; ++k) lse_comb(M, S, smx[0][k], ssm[0][k]);
    const float lse = M + __logf(S);
    for (int i = tid; i < NS; i += 256) log_pi[i] = prior[i] - lse;
  }
}

// ---------- phase A2: T_prob[m][n] = exp(Tu[m][n] - colLSE[n]) as bf16 ----------
__global__ void __launch_bounds__(256)
prep_tprob(const float* __restrict__ Tu, const float* __restrict__ colLSE,
           unsigned short* __restrict__ Tp) {
  const int i = (blockIdx.x * 256 + threadIdx.x) * 4;
  const float4 tu = *(const float4*)(Tu + i);
  const float4 cl = *(const float4*)(colLSE + (i & (NS - 1)));
  ushort4 o;
  o.x = f2bf(__expf(tu.x - cl.x));
  o.y = f2bf(__expf(tu.y - cl.y));
  o.z = f2bf(__expf(tu.z - cl.z));
  o.w = f2bf(__expf(tu.w - cl.w));
  *(ushort4*)(Tp + i) = o;
}

// ---------- phase A3: emission row LSE + gather, TRANSPOSED write ----------
// emitT[n][j] = emission[n][tok[j]] - rowLSE[n]  (n-row contiguous in j -> coalesced)
__global__ void __launch_bounds__(256)
prep_emit(const float* __restrict__ Em, const int* __restrict__ tok,
          float* __restrict__ emitT) {
  __shared__ float wm[4], wsv[4];
  const int n = blockIdx.x;
  const int tid = threadIdx.x;
  const float* row = Em + (size_t)n * NV;
  float mx = -INFINITY, s = 0.f;
  for (int i = tid; i < NV; i += 256) lse_add(mx, s, row[i]);
  for (int o = 1; o < 64; o <<= 1) {
    float m2 = __shfl_xor(mx, o), s2 = __shfl_xor(s, o);
    lse_comb(mx, s, m2, s2);
  }
  const int wv = tid >> 6, ln = tid & 63;
  if (ln == 0) { wm[wv] = mx; wsv[wv] = s; }
  __syncthreads();
  float M = wm[0], S = wsv[0];
  for (int k = 1; k < 4; ++k) lse_comb(M, S, wm[k], wsv[k]);
  const float lse = M + __logf(S);
  for (int j = tid; j < NJ; j += 256)
    emitT[(size_t)n * NJ + j] = row[tok[j]] - lse;   // coalesced write; row L2-hot
}

// ---------- phase B: 64 independent 1-wave units, flag-synced via L3 ----------
// Unit u owns rows [u*16, u*16+16). T slice in 128 VGPRs. B-frags read directly
// from L3 (sc0 sc1). exp published pre-scaled bf16 with stale scale s_{t+1}=gmax_t.
__global__ void __launch_bounds__(64, 1)
hmm64(const unsigned short* __restrict__ Tp, const float* __restrict__ emitT,
      const float* __restrict__ log_pi, const int* __restrict__ length,
      unsigned short* __restrict__ expb,   // [2][NB][NS] bf16
      float* __restrict__ wgm,             // [2][64][16] f32
      unsigned int* __restrict__ flags,    // [64] u32 @ 64B stride
      float* __restrict__ out) {
  const int u    = blockIdx.x;    // 0..63
  const int lane = threadIdx.x;   // 0..63
  const int b2   = lane & 15;     // batch (B-col, C/D col)
  const int kg   = lane >> 4;     // 0..3
  const int m0   = u * 16 + kg * 4;   // this lane's 4 output rows (C/D row=kg*4+r)

  // A-fragments (validated r3/r4): row = u*16+(lane&15), k = i*32 + kg*8 + j
  short8 tf[32];
  {
    const unsigned short* tb = Tp + (size_t)(u * 16 + b2) * NS + kg * 8;
#pragma unroll
    for (int i = 0; i < 32; ++i) tf[i] = *(const short8*)(tb + i * 32);
  }

  int myLen = length[b2];
  myLen = myLen < 1 ? 1 : (myLen > NT ? NT : myLen);

  // ---- phase A: alpha0[m0..m0+3][b2], publish wg-max
  float al[4];
  {
    const float4 lp = *(const float4*)(log_pi + m0);
#pragma unroll
    for (int r = 0; r < 4; ++r)
      al[r] = emitT[(size_t)(m0 + r) * NJ + b2 * NT] + lp[r];
  }
  {
    float wm = fmaxf(fmaxf(al[0], al[1]), fmaxf(al[2], al[3]));
    wm = fmaxf(wm, __shfl_xor(wm, 16));
    wm = fmaxf(wm, __shfl_xor(wm, 32));
    if (lane < 16)
      __hip_atomic_store(wgm + (size_t)u * 16 + lane, wm,
                         __ATOMIC_RELAXED, __HIP_MEMORY_SCOPE_AGENT);
  }
  asm volatile("s_waitcnt vmcnt(0)" ::: "memory");
  if (lane == 0)
    __hip_atomic_store(flags + u * 16, 1u, __ATOMIC_RELAXED, __HIP_MEMORY_SCOPE_AGENT);

  // poll all flags >= 1
  for (;;) {
    unsigned int f;
    asm volatile("global_load_dword %0, %1, off sc0 sc1" : "=v"(f)
                 : "v"(flags + lane * 16) : "memory");
    asm volatile("s_waitcnt vmcnt(0)" ::: "memory");
    if (__all((int)(f >= 1u))) break;
    __builtin_amdgcn_s_sleep(2);
  }
  __builtin_amdgcn_sched_barrier(0);

  // gmax_0 -> s_cur; publish exp_0 = e^{alpha0 - s_cur}
  float s_cur;
  {
    float wv_[16];
    const float* wb = wgm + b2;
#pragma unroll
    for (int i = 0; i < 16; ++i)
      asm volatile("global_load_dword %0, %1, off sc0 sc1" : "=v"(wv_[i])
                   : "v"(wb + (kg * 16 + i) * 16) : "memory");
    asm volatile("s_waitcnt vmcnt(0)" ::: "memory");
    __builtin_amdgcn_sched_barrier(0);
    float g = wv_[0];
#pragma unroll
    for (int i = 1; i < 16; ++i) g = fmaxf(g, wv_[i]);
    g = fmaxf(g, __shfl_xor(g, 16));
    g = fmaxf(g, __shfl_xor(g, 32));
    s_cur = g;
  }
  {
    uint2_t pk;
    pk.x = (unsigned int)f2bf(__expf(al[0] - s_cur)) |
           ((unsigned int)f2bf(__expf(al[1] - s_cur)) << 16);
    pk.y = (unsigned int)f2bf(__expf(al[2] - s_cur)) |
           ((unsigned int)f2bf(__expf(al[3] - s_cur)) << 16);
    unsigned short* dst = expb + (size_t)b2 * NS + m0;
    asm volatile("global_store_dwordx2 %0, %1, off sc0 sc1" :: "v"(dst), "v"(pk) : "memory");
  }
  asm volatile("s_waitcnt vmcnt(0)" ::: "memory");
  if (lane == 0)
    __hip_atomic_store(flags + u * 16, 2u, __ATOMIC_RELAXED, __HIP_MEMORY_SCOPE_AGENT);

  // ---- main loop: step t consumes exp_t (scale s_cur), produces exp_{t+1}
  for (int t = 0; t < NT - 1; ++t) {
    const unsigned int tgt = (unsigned int)(t + 2);
    for (;;) {
      unsigned int f;
      asm volatile("global_load_dword %0, %1, off sc0 sc1" : "=v"(f)
                   : "v"(flags + lane * 16) : "memory");
      asm volatile("s_waitcnt vmcnt(0)" ::: "memory");
      if (__all((int)(f >= tgt))) break;
      __builtin_amdgcn_s_sleep(2);
    }
    __builtin_amdgcn_sched_barrier(0);

    // issue: 32 B-frags + 16 wgm + 4 emit (all L3-coherent)
    float4 bfr[32];
    {
      const unsigned short* bp = expb + (size_t)(t & 1) * (NB * NS) + (size_t)b2 * NS + kg * 8;
#pragma unroll
      for (int i = 0; i < 32; ++i)
        asm volatile("global_load_dwordx4 %0, %1, off sc0 sc1" : "=v"(bfr[i])
                     : "v"(bp + i * 32) : "memory");
    }
    float wv_[16];
    {
      const float* wb = wgm + (size_t)(t & 1) * 1024 + b2;
#pragma unroll
      for (int i = 0; i < 16; ++i)
        asm volatile("global_load_dword %0, %1, off sc0 sc1" : "=v"(wv_[i])
                     : "v"(wb + (kg * 16 + i) * 16) : "memory");
    }
    float em[4];
    {
      const float* ep = emitT + (size_t)m0 * NJ + b2 * NT + (t + 1);
#pragma unroll
      for (int r = 0; r < 4; ++r)
        asm volatile("global_load_dword %0, %1, off" : "=v"(em[r])
                     : "v"(ep + (size_t)r * NJ) : "memory");
    }
    asm volatile("s_waitcnt vmcnt(0)" ::: "memory");
    __builtin_amdgcn_sched_barrier(0);

    // gmax_t -> s_next
    float g = wv_[0];
#pragma unroll
    for (int i = 1; i < 16; ++i) g = fmaxf(g, wv_[i]);
    g = fmaxf(g, __shfl_xor(g, 16));
    g = fmaxf(g, __shfl_xor(g, 32));
    const float s_next = g;

    // MFMA: S[m][b] = sum_k T[m][k] * exp_t[b][k]; 4 independent acc chains
    f32x4 a0 = {0.f, 0.f, 0.f, 0.f}, a1 = a0, a2 = a0, a3 = a0;
#pragma unroll
    for (int i = 0; i < 32; i += 4) {
      a0 = __builtin_amdgcn_mfma_f32_16x16x32_bf16(tf[i + 0], __builtin_bit_cast(short8, bfr[i + 0]), a0, 0, 0, 0);
      a1 = __builtin_amdgcn_mfma_f32_16x16x32_bf16(tf[i + 1], __builtin_bit_cast(short8, bfr[i + 1]), a1, 0, 0, 0);
      a2 = __builtin_amdgcn_mfma_f32_16x16x32_bf16(tf[i + 2], __builtin_bit_cast(short8, bfr[i + 2]), a2, 0, 0, 0);
      a3 = __builtin_amdgcn_mfma_f32_16x16x32_bf16(tf[i + 3], __builtin_bit_cast(short8, bfr[i + 3]), a3, 0, 0, 0);
    }
    const f32x4 Sv = (a0 + a1) + (a2 + a3);

    // output duty (unit 0 only): out[b] = s_cur + ln sum_k exp_t[b][k]
    if (u == 0 && __any((int)(myLen - 1 == t))) {
      float sum = 0.f;
#pragma unroll
      for (int i = 0; i < 32; ++i) {
        const short8 v = __builtin_bit_cast(short8, bfr[i]);
#pragma unroll
        for (int j = 0; j < 8; ++j) sum += bf2f((unsigned short)v[j]);
      }
      sum += __shfl_xor(sum, 16);
      sum += __shfl_xor(sum, 32);
      if (lane < 16 && myLen - 1 == t) out[lane] = s_cur + __logf(sum);
    }

    // epilogue: alpha_{t+1} = emit + s_cur + ln(S); publish exp & wg-max
#pragma unroll
    for (int r = 0; r < 4; ++r)
      al[r] = em[r] + s_cur + 0.6931471805599453f * __log2f(Sv[r]);
    {
      float wm = fmaxf(fmaxf(al[0], al[1]), fmaxf(al[2], al[3]));
      wm = fmaxf(wm, __shfl_xor(wm, 16));
      wm = fmaxf(wm, __shfl_xor(wm, 32));
      if (lane < 16)
        __hip_atomic_store(wgm + (size_t)((t + 1) & 1) * 1024 + u * 16 + lane, wm,
                           __ATOMIC_RELAXED, __HIP_MEMORY_SCOPE_AGENT);
    }
    {
      uint2_t pk;
      pk.x = (unsigned int)f2bf(__expf(al[0] - s_next)) |
             ((unsigned int)f2bf(__expf(al[1] - s_next)) << 16);
      pk.y = (unsigned int)f2bf(__expf(al[2] - s_next)) |
             ((unsigned int)f2bf(__expf(al[3] - s_next)) << 16);
      unsigned short* dst = expb + (size_t)((t + 1) & 1) * (NB * NS) + (size_t)b2 * NS + m0;
      asm volatile("global_store_dwordx2 %0, %1, off sc0 sc1" :: "v"(dst), "v"(pk) : "memory");
    }
    asm volatile("s_waitcnt vmcnt(0)" ::: "memory");
    if (lane == 0)
      __hip_atomic_store(flags + u * 16, (unsigned int)(t + 3),
                         __ATOMIC_RELAXED, __HIP_MEMORY_SCOPE_AGENT);
    s_cur = s_next;
  }

  // ---- tail: len == NT outputs from exp_{NT-1} (buffer 1, scale s_cur)
  if (u == 0 && __any((int)(myLen == NT))) {
    const unsigned int tgt = (unsigned int)(NT + 1);
    for (;;) {
      unsigned int f;
      asm volatile("global_load_dword %0, %1, off sc0 sc1" : "=v"(f)
                   : "v"(flags + lane * 16) : "memory");
      asm volatile("s_waitcnt vmcnt(0)" ::: "memory");
      if (__all((int)(f >= tgt))) break;
      __builtin_amdgcn_s_sleep(2);
    }
    __builtin_amdgcn_sched_barrier(0);
    float4 bfr[32];
    const unsigned short* bp = expb + (size_t)((NT - 1) & 1) * (NB * NS) + (size_t)b2 * NS + kg * 8;
#pragma unroll
    for (int i = 0; i < 32; ++i)
      asm volatile("global_load_dwordx4 %0, %1, off sc0 sc1" : "=v"(bfr[i])
                   : "v"(bp + i * 32) : "memory");
    asm volatile("s_waitcnt vmcnt(0)" ::: "memory");
    __builtin_amdgcn_sched_barrier(0);
    float sum = 0.f;
#pragma unroll
    for (int i = 0; i < 32; ++i) {
      const short8 v = __builtin_bit_cast(short8, bfr[i]);
#pragma unroll
      for (int j = 0; j < 8; ++j) sum += bf2f((unsigned short)v[j]);
    }
    sum += __shfl_xor(sum, 16);
    sum += __shfl_xor(sum, 32);
    if (lane < 16 && myLen == NT) out[lane] = s_cur + __logf(sum);
  }
}

// ---------- launch ----------
extern "C" void kernel_launch(void* const* d_in, const int* in_sizes, int n_in,
                              void* d_out, int out_size, void* d_ws, size_t ws_size,
                              hipStream_t stream) {
  const float* Em = (const float*)d_in[0];   // emission (N,V)
  const float* Tu = (const float*)d_in[1];   // transition (N,N)
  const float* Pr = (const float*)d_in[2];   // priors (N,)
  const int*   tok = (const int*)d_in[3];    // (B,T)
  const int*   len = (const int*)d_in[4];    // (B,)
  float* out = (float*)d_out;
  char* ws = (char*)d_ws;

  float* colLSE       = (float*)(ws + 0);             // 4 KB
  float* log_pi       = (float*)(ws + 4096);          // 4 KB
  unsigned int* flags = (unsigned int*)(ws + 8192);   // 4 KB (64 x 64B)
  float* wgm          = (float*)(ws + 12288);         // 8 KB [2][64][16]
  unsigned short* expb = (unsigned short*)(ws + 20480); // 64 KB [2][16][1024]
  unsigned short* Tp  = (unsigned short*)(ws + (256 << 10)); // 2 MB bf16
  float* emitT        = (float*)(ws + (4u << 20));    // 8 MB [1024][2048]

  hipMemsetAsync(flags, 0, 4096, stream);   // ws poisoned 0xAA before each call
  prep_trans<<<17, 256, 0, stream>>>(Tu, Pr, colLSE, log_pi);
  prep_tprob<<<(NS * NS) / (256 * 4), 256, 0, stream>>>(Tu, colLSE, Tp);
  prep_emit<<<NS, 256, 0, stream>>>(Em, tok, emitT);

  void* args[] = {(void*)&Tp, (void*)&emitT, (void*)&log_pi, (void*)&len,
                  (void*)&expb, (void*)&wgm, (void*)&flags, (void*)&out};
  hipError_t e = hipLaunchCooperativeKernel((void*)hmm64, dim3(64), dim3(64),
                                            args, 0, stream);
  if (e != hipSuccess) {
    // 64 one-wave blocks on a 256-CU device are trivially co-resident
    hmm64<<<dim3(64), dim3(64), 0, stream>>>(Tp, emitT, log_pi, len,
                                             expb, wgm, flags, out);
  }
}